// Round 8
// baseline (517.021 us; speedup 1.0000x reference)
//
#include <hip/hip_runtime.h>
#include <hip/hip_bf16.h>
#include <math.h>

#define B_ 4
#define S_ 2048
#define D_ 512
#define H_ 8
#define DK_ 64

typedef __bf16 bf16x8 __attribute__((ext_vector_type(8)));
typedef float f32x16 __attribute__((ext_vector_type(16)));
typedef float f32x4 __attribute__((ext_vector_type(4)));

static __device__ __forceinline__ unsigned short f2bf(float f) {
    unsigned int u = __builtin_bit_cast(unsigned int, f);
    unsigned int r = (u + 0x7FFFu + ((u >> 16) & 1u)) >> 16;
    return (unsigned short)r;
}

// ---- x (f32) -> bf16, vectorized ----
__global__ void k_convert_x(const float* __restrict__ x, unsigned short* __restrict__ xb, int n4) {
    int i = blockIdx.x * blockDim.x + threadIdx.x;
    if (i >= n4) return;
    const float4 v = reinterpret_cast<const float4*>(x)[i];
    ushort4 o;
    o.x = f2bf(v.x); o.y = f2bf(v.y); o.z = f2bf(v.z); o.w = f2bf(v.w);
    reinterpret_cast<ushort4*>(xb)[i] = o;
}

// ---- W_Q/W_K [H][D][DK] f32 -> [H][DK][D] bf16 ----
__global__ void k_transpose_w(const float* __restrict__ wq, const float* __restrict__ wk,
                              unsigned short* __restrict__ wqT, unsigned short* __restrict__ wkT) {
    int idx = blockIdx.x * blockDim.x + threadIdx.x;
    const int n = H_ * DK_ * D_;
    const float* src = idx < n ? wq : wk;
    unsigned short* dst = idx < n ? wqT : wkT;
    int o = idx < n ? idx : idx - n;
    int d  = o % D_;
    int hk = o / D_;
    int k  = hk % DK_;
    int h  = hk / DK_;
    dst[o] = f2bf(src[(h * D_ + d) * DK_ + k]);
}

// ---- decay table tab[h][n] = gamma_h^n ----
__global__ void k_decay(float* __restrict__ tab) {
    int i = blockIdx.x * blockDim.x + threadIdx.x;
    if (i >= H_ * S_) return;
    int h = i / S_;
    int n = i % S_;
    double xv = -3.4657359027997265 - (double)h * (2.772588722239781 / 7.0);
    double g = 1.0 - exp(xv);
    tab[i] = (float)pow(g, (double)n);
}

// ---- zero output 0 (reference out == 0 exactly: GroupNorm group-size 1) ----
__global__ void k_zero(float4* __restrict__ p, int n4) {
    int i = blockIdx.x * blockDim.x + threadIdx.x;
    if (i < n4) { float4 z = {0.f, 0.f, 0.f, 0.f}; p[i] = z; }
}

// ---- projection GEMM, fused all heads: [B*S, 512] x [512, 1024(Q||K)] ----
__global__ __launch_bounds__(256) void k_proj(const unsigned short* __restrict__ xb,
                                              const unsigned short* __restrict__ wqT,
                                              const unsigned short* __restrict__ wkT,
                                              unsigned short* __restrict__ qb,
                                              unsigned short* __restrict__ kb) {
    const int lane = threadIdx.x & 63;
    const int wave = threadIdx.x >> 6;
    const int m0 = blockIdx.x * 32;
    const int ncol0 = blockIdx.y * 512 + wave * 128;
    const int row  = lane & 31;
    const int koff = (lane >> 5) * 8;

    const unsigned short* wt = (ncol0 >> 9) ? wkT : wqT;
    unsigned short* outp     = (ncol0 >> 9) ? kb  : qb;

    const unsigned short* aptr = xb + (size_t)(m0 + row) * D_ + koff;
    const unsigned short* bptr0 = wt + (size_t)((ncol0 +  0 + row) & 511) * D_ + koff;
    const unsigned short* bptr1 = wt + (size_t)((ncol0 + 32 + row) & 511) * D_ + koff;
    const unsigned short* bptr2 = wt + (size_t)((ncol0 + 64 + row) & 511) * D_ + koff;
    const unsigned short* bptr3 = wt + (size_t)((ncol0 + 96 + row) & 511) * D_ + koff;

    f32x16 acc0 = {}, acc1 = {}, acc2 = {}, acc3 = {};
    for (int kk = 0; kk < D_; kk += 16) {
        bf16x8 a = *reinterpret_cast<const bf16x8*>(aptr + kk);
        acc0 = __builtin_amdgcn_mfma_f32_32x32x16_bf16(a, *reinterpret_cast<const bf16x8*>(bptr0 + kk), acc0, 0, 0, 0);
        acc1 = __builtin_amdgcn_mfma_f32_32x32x16_bf16(a, *reinterpret_cast<const bf16x8*>(bptr1 + kk), acc1, 0, 0, 0);
        acc2 = __builtin_amdgcn_mfma_f32_32x32x16_bf16(a, *reinterpret_cast<const bf16x8*>(bptr2 + kk), acc2, 0, 0, 0);
        acc3 = __builtin_amdgcn_mfma_f32_32x32x16_bf16(a, *reinterpret_cast<const bf16x8*>(bptr3 + kk), acc3, 0, 0, 0);
    }

    const f32x16* accs[4] = { &acc0, &acc1, &acc2, &acc3 };
#pragma unroll
    for (int nb = 0; nb < 4; ++nb) {
        int n = ncol0 + nb * 32 + (lane & 31);
        int h = (n >> 6) & 7;
        int k = n & 63;
#pragma unroll
        for (int r = 0; r < 16; ++r) {
            int rowD = (r & 3) + 8 * (r >> 2) + 4 * (lane >> 5);
            int m = m0 + rowD;
            int bidx = m >> 11, s = m & 2047;
            outp[(((size_t)bidx * H_ + h) * S_ + s) * DK_ + k] = f2bf((*accs[nb])[r]);
        }
    }
}

// ---- scores: round-7 structure, body wrapped in an idempotent 4x rep loop ----
// MEASUREMENT ROUND: the 4x rep makes this ONE dispatch ~560-600us — longer
// than the harness's 330us poison fills — so it lands in rocprof's top-5 and
// we finally see FETCH_SIZE / WRITE_SIZE / MfmaUtil / VALUBusy / LDS_CONFLICT
// for the score kernel. Writing identical values 4x is deterministic.
__global__ __launch_bounds__(256) void k_score(const unsigned short* __restrict__ qb,
                                               const unsigned short* __restrict__ kb,
                                               const float* __restrict__ tab,
                                               float* __restrict__ aout) {
    const int lane = threadIdx.x & 63;
    const int w    = threadIdx.x >> 6;
    const int bh   = blockIdx.y;
    const int h    = bh & (H_ - 1);
    const int p    = blockIdx.x;                 // 0..15
    float* ablk = aout + (size_t)bh * S_ * S_;
    const float* th = tab + h * S_;

    __shared__ float tile[64 * 256];             // 64KB

    const int col  = lane & 31;
    const int hi   = lane >> 5;
    const int koff = hi * 8;

    const float c1 = 1.0f / th[col];
    float grc[16];
    int rowDv[16];
#pragma unroll
    for (int r = 0; r < 16; ++r) {
        rowDv[r] = (r & 3) + 8 * (r >> 2) + 4 * hi;
        grc[r] = th[rowDv[r]] * c1;
    }

#pragma unroll 1
    for (int rep = 0; rep < 4; ++rep) {
    for (int pp = 0; pp < 2; ++pp) {
        const int panel = pp ? (31 - p) : p;
        const int s0 = panel * 64;
        const int qq = panel >> 2;
        const int rb = panel & 3;

        bf16x8 qf[2][4];
#pragma unroll
        for (int rg = 0; rg < 2; ++rg) {
            const unsigned short* qp = qb + ((size_t)bh * S_ + s0 + rg * 32 + col) * DK_ + koff;
#pragma unroll
            for (int i = 0; i < 4; ++i)
                qf[rg][i] = *reinterpret_cast<const bf16x8*>(qp + 16 * i);
        }

        for (int st = 0; st < 8; ++st) {
            const int t0 = st * 256;
            if (st <= qq) {
                const int ct0 = t0 + w * 64;
                const bool active = (st < qq) || (w <= rb);
                if (active) {
                    f32x16 acc[2][2] = {{{}, {}}, {{}, {}}};
#pragma unroll
                    for (int cg = 0; cg < 2; ++cg) {
                        const unsigned short* kp = kb + ((size_t)bh * S_ + ct0 + cg * 32 + col) * DK_ + koff;
                        bf16x8 kf0 = *reinterpret_cast<const bf16x8*>(kp);
                        bf16x8 kf1 = *reinterpret_cast<const bf16x8*>(kp + 16);
                        bf16x8 kf2 = *reinterpret_cast<const bf16x8*>(kp + 32);
                        bf16x8 kf3 = *reinterpret_cast<const bf16x8*>(kp + 48);
#pragma unroll
                        for (int rg = 0; rg < 2; ++rg) {
                            acc[rg][cg] = __builtin_amdgcn_mfma_f32_32x32x16_bf16(qf[rg][0], kf0, acc[rg][cg], 0, 0, 0);
                            acc[rg][cg] = __builtin_amdgcn_mfma_f32_32x32x16_bf16(qf[rg][1], kf1, acc[rg][cg], 0, 0, 0);
                            acc[rg][cg] = __builtin_amdgcn_mfma_f32_32x32x16_bf16(qf[rg][2], kf2, acc[rg][cg], 0, 0, 0);
                            acc[rg][cg] = __builtin_amdgcn_mfma_f32_32x32x16_bf16(qf[rg][3], kf3, acc[rg][cg], 0, 0, 0);
                        }
                    }
                    if (st < qq || w < rb) {
#pragma unroll
                        for (int rg = 0; rg < 2; ++rg) {
#pragma unroll
                            for (int cg = 0; cg < 2; ++cg) {
                                const float sc = th[s0 + rg * 32 - ct0 - cg * 32];
#pragma unroll
                                for (int r = 0; r < 16; ++r)
                                    tile[(rg * 32 + rowDv[r]) * 256 + w * 64 + cg * 32 + col] =
                                        acc[rg][cg][r] * grc[r] * sc;
                            }
                        }
                    } else {
#pragma unroll
                        for (int rg = 0; rg < 2; ++rg) {
#pragma unroll
                            for (int cg = 0; cg < 2; ++cg) {
                                const int dbase = 32 * (rg - cg);
#pragma unroll
                                for (int r = 0; r < 16; ++r) {
                                    int d = dbase + rowDv[r] - col;
                                    float v = (d >= 0) ? acc[rg][cg][r] * th[d] : 0.0f;
                                    tile[(rg * 32 + rowDv[r]) * 256 + w * 64 + cg * 32 + col] = v;
                                }
                            }
                        }
                    }
                } else {
                    f32x4 z = {0.f, 0.f, 0.f, 0.f};
#pragma unroll
                    for (int i = 0; i < 16; ++i) {
                        int r = i * 4 + (lane >> 4);
                        int c = (lane & 15) * 4;
                        *reinterpret_cast<f32x4*>(&tile[r * 256 + w * 64 + c]) = z;
                    }
                }
                __syncthreads();
#pragma unroll
                for (int r = 0; r < 16; ++r) {
                    int row = w * 16 + r;
                    f32x4 v = *reinterpret_cast<const f32x4*>(&tile[row * 256 + lane * 4]);
                    *reinterpret_cast<f32x4*>(ablk + (size_t)(s0 + row) * S_ + t0 + lane * 4) = v;
                }
                __syncthreads();
            } else {
                f32x4 z = {0.f, 0.f, 0.f, 0.f};
#pragma unroll
                for (int r = 0; r < 16; ++r) {
                    int row = w * 16 + r;
                    *reinterpret_cast<f32x4*>(ablk + (size_t)(s0 + row) * S_ + t0 + lane * 4) = z;
                }
            }
        }
    }
    }  // rep
}

extern "C" void kernel_launch(void* const* d_in, const int* in_sizes, int n_in,
                              void* d_out, int out_size, void* d_ws, size_t ws_size,
                              hipStream_t stream) {
    const float* x  = (const float*)d_in[0];
    const float* wq = (const float*)d_in[1];
    const float* wk = (const float*)d_in[2];

    char* ws = (char*)d_ws;
    unsigned short* xb  = (unsigned short*)(ws);               //  8,388,608 B
    unsigned short* wqT = (unsigned short*)(ws + 8388608);     //    524,288 B
    unsigned short* wkT = (unsigned short*)(ws + 8912896);     //    524,288 B
    unsigned short* qb  = (unsigned short*)(ws + 9437184);     //  8,388,608 B
    unsigned short* kb  = (unsigned short*)(ws + 17825792);    //  8,388,608 B
    float*          tab = (float*)(ws + 26214400);             //     65,536 B

    float* out0 = (float*)d_out;
    float* aout = (float*)d_out + (size_t)B_ * S_ * D_;

    hipLaunchKernelGGL(k_convert_x, dim3((B_*S_*D_/4 + 255)/256), dim3(256), 0, stream,
                       x, xb, B_*S_*D_/4);
    hipLaunchKernelGGL(k_transpose_w, dim3((2*H_*DK_*D_ + 255)/256), dim3(256), 0, stream,
                       wq, wk, wqT, wkT);
    hipLaunchKernelGGL(k_decay, dim3((H_*S_ + 255)/256), dim3(256), 0, stream, tab);
    hipLaunchKernelGGL(k_zero, dim3((B_*S_*D_/4 + 255)/256), dim3(256), 0, stream,
                       (float4*)out0, B_*S_*D_/4);
    hipLaunchKernelGGL(k_proj, dim3(B_*S_/32, 2), dim3(256), 0, stream,
                       xb, wqT, wkT, qb, kb);
    hipLaunchKernelGGL(k_score, dim3(16, B_*H_), dim3(256), 0, stream,
                       qb, kb, tab, aout);
}

// Round 9
// 189.603 us; speedup vs baseline: 2.7269x; 2.7269x over previous
//
#include <hip/hip_runtime.h>
#include <hip/hip_bf16.h>
#include <math.h>

#define B_ 4
#define S_ 2048
#define D_ 512
#define H_ 8
#define DK_ 64

typedef __bf16 bf16x8 __attribute__((ext_vector_type(8)));
typedef float f32x16 __attribute__((ext_vector_type(16)));
typedef float f32x4 __attribute__((ext_vector_type(4)));

static __device__ __forceinline__ unsigned short f2bf(float f) {
    unsigned int u = __builtin_bit_cast(unsigned int, f);
    unsigned int r = (u + 0x7FFFu + ((u >> 16) & 1u)) >> 16;
    return (unsigned short)r;
}

// ---- x (f32) -> bf16, vectorized ----
__global__ void k_convert_x(const float* __restrict__ x, unsigned short* __restrict__ xb, int n4) {
    int i = blockIdx.x * blockDim.x + threadIdx.x;
    if (i >= n4) return;
    const float4 v = reinterpret_cast<const float4*>(x)[i];
    ushort4 o;
    o.x = f2bf(v.x); o.y = f2bf(v.y); o.z = f2bf(v.z); o.w = f2bf(v.w);
    reinterpret_cast<ushort4*>(xb)[i] = o;
}

// ---- W_Q/W_K [H][D][DK] f32 -> [H][DK][D] bf16 ----
__global__ void k_transpose_w(const float* __restrict__ wq, const float* __restrict__ wk,
                              unsigned short* __restrict__ wqT, unsigned short* __restrict__ wkT) {
    int idx = blockIdx.x * blockDim.x + threadIdx.x;
    const int n = H_ * DK_ * D_;
    const float* src = idx < n ? wq : wk;
    unsigned short* dst = idx < n ? wqT : wkT;
    int o = idx < n ? idx : idx - n;
    int d  = o % D_;
    int hk = o / D_;
    int k  = hk % DK_;
    int h  = hk / DK_;
    dst[o] = f2bf(src[(h * D_ + d) * DK_ + k]);
}

// ---- decay table tab[h][n] = gamma_h^n ----
__global__ void k_decay(float* __restrict__ tab) {
    int i = blockIdx.x * blockDim.x + threadIdx.x;
    if (i >= H_ * S_) return;
    int h = i / S_;
    int n = i % S_;
    double xv = -3.4657359027997265 - (double)h * (2.772588722239781 / 7.0);
    double g = 1.0 - exp(xv);
    tab[i] = (float)pow(g, (double)n);
}

// ---- zero output 0 (reference out == 0 exactly: GroupNorm group-size 1) ----
__global__ void k_zero(float4* __restrict__ p, int n4) {
    int i = blockIdx.x * blockDim.x + threadIdx.x;
    if (i < n4) { float4 z = {0.f, 0.f, 0.f, 0.f}; p[i] = z; }
}

// ---- zero-fill strictly-upper supertiles of A ----
// grid (112, 32): block = one 64x256 supertile (64KB) of one bh. Pure
// barrier-free streaming stores, wave writes full 1KB row-chunks (the
// 6.6 TB/s harness-fill pattern). Total 224 MB.
__global__ __launch_bounds__(256) void k_fill_upper(float* __restrict__ aout) {
    const int bh = blockIdx.y;
    int r = blockIdx.x;                       // 0..111
    int g = 0, cum = 0;
    for (; g < 7; ++g) { int cnt = 4 * (7 - g); if (r < cum + cnt) break; cum += cnt; }
    const int rr  = r - cum;
    const int per = 7 - g;
    const int panel = g * 4 + rr / per;
    const int st    = g + 1 + rr % per;

    float* base = aout + (size_t)bh * S_ * S_ + (size_t)(panel * 64) * S_ + st * 256;
    const int t = threadIdx.x;
    f32x4 z = {0.f, 0.f, 0.f, 0.f};
#pragma unroll
    for (int j = 0; j < 16; ++j) {
        int u = t + j * 256;                  // f32x4 slot in 64x256 supertile
        int row = u >> 6;
        int c4  = u & 63;
        *reinterpret_cast<f32x4*>(base + (size_t)row * S_ + c4 * 4) = z;
    }
}

// ---- projection GEMM, fused all heads: [B*S, 512] x [512, 1024(Q||K)] ----
__global__ __launch_bounds__(256) void k_proj(const unsigned short* __restrict__ xb,
                                              const unsigned short* __restrict__ wqT,
                                              const unsigned short* __restrict__ wkT,
                                              unsigned short* __restrict__ qb,
                                              unsigned short* __restrict__ kb) {
    const int lane = threadIdx.x & 63;
    const int wave = threadIdx.x >> 6;
    const int m0 = blockIdx.x * 32;
    const int ncol0 = blockIdx.y * 512 + wave * 128;
    const int row  = lane & 31;
    const int koff = (lane >> 5) * 8;

    const unsigned short* wt = (ncol0 >> 9) ? wkT : wqT;
    unsigned short* outp     = (ncol0 >> 9) ? kb  : qb;

    const unsigned short* aptr = xb + (size_t)(m0 + row) * D_ + koff;
    const unsigned short* bptr0 = wt + (size_t)((ncol0 +  0 + row) & 511) * D_ + koff;
    const unsigned short* bptr1 = wt + (size_t)((ncol0 + 32 + row) & 511) * D_ + koff;
    const unsigned short* bptr2 = wt + (size_t)((ncol0 + 64 + row) & 511) * D_ + koff;
    const unsigned short* bptr3 = wt + (size_t)((ncol0 + 96 + row) & 511) * D_ + koff;

    f32x16 acc0 = {}, acc1 = {}, acc2 = {}, acc3 = {};
    for (int kk = 0; kk < D_; kk += 16) {
        bf16x8 a = *reinterpret_cast<const bf16x8*>(aptr + kk);
        acc0 = __builtin_amdgcn_mfma_f32_32x32x16_bf16(a, *reinterpret_cast<const bf16x8*>(bptr0 + kk), acc0, 0, 0, 0);
        acc1 = __builtin_amdgcn_mfma_f32_32x32x16_bf16(a, *reinterpret_cast<const bf16x8*>(bptr1 + kk), acc1, 0, 0, 0);
        acc2 = __builtin_amdgcn_mfma_f32_32x32x16_bf16(a, *reinterpret_cast<const bf16x8*>(bptr2 + kk), acc2, 0, 0, 0);
        acc3 = __builtin_amdgcn_mfma_f32_32x32x16_bf16(a, *reinterpret_cast<const bf16x8*>(bptr3 + kk), acc3, 0, 0, 0);
    }

    const f32x16* accs[4] = { &acc0, &acc1, &acc2, &acc3 };
#pragma unroll
    for (int nb = 0; nb < 4; ++nb) {
        int n = ncol0 + nb * 32 + (lane & 31);
        int h = (n >> 6) & 7;
        int k = n & 63;
#pragma unroll
        for (int r = 0; r < 16; ++r) {
            int rowD = (r & 3) + 8 * (r >> 2) + 4 * (lane >> 5);
            int m = m0 + rowD;
            int bidx = m >> 11, s = m & 2047;
            outp[(((size_t)bidx * H_ + h) * S_ + s) * DK_ + k] = f2bf((*accs[nb])[r]);
        }
    }
}

// ---- scores, lower-triangle only ----
// 1D grid 512 blocks. id -> (bh, p) mapped so each bh's 16 blocks land on
// exactly 2 XCD classes (id%8): K/Q slices stay L2-resident per XCD.
// Block: panels p and 31-p, supertiles st<=qq only -> uniformly 9 x 64KB.
// Compute -> LDS [64][256] -> full-1KB-row streaming stores. Strictly-upper
// supertiles are handled by k_fill_upper (barrier-free).
__global__ __launch_bounds__(256) void k_score(const unsigned short* __restrict__ qb,
                                               const unsigned short* __restrict__ kb,
                                               const float* __restrict__ tab,
                                               float* __restrict__ aout) {
    const int lane = threadIdx.x & 63;
    const int w    = threadIdx.x >> 6;
    const int id   = blockIdx.x;
    const int c    = id & 7, sidx = id >> 3;
    const int bh   = (c >> 1) + 4 * (sidx >> 3);
    const int p    = ((sidx & 7) << 1) | (c & 1);
    const int h    = bh & (H_ - 1);
    float* ablk = aout + (size_t)bh * S_ * S_;
    const float* th = tab + h * S_;

    __shared__ float tile[64 * 256];             // 64KB

    const int col  = lane & 31;
    const int hi   = lane >> 5;
    const int koff = hi * 8;

    const float c1 = 1.0f / th[col];
    float grc[16];
    int rowDv[16];
#pragma unroll
    for (int r = 0; r < 16; ++r) {
        rowDv[r] = (r & 3) + 8 * (r >> 2) + 4 * hi;
        grc[r] = th[rowDv[r]] * c1;
    }

    for (int pp = 0; pp < 2; ++pp) {
        const int panel = pp ? (31 - p) : p;
        const int s0 = panel * 64;
        const int qq = panel >> 2;               // diagonal supertile index
        const int rb = panel & 3;                // diagonal wave within it

        bf16x8 qf[2][4];
#pragma unroll
        for (int rg = 0; rg < 2; ++rg) {
            const unsigned short* qp = qb + ((size_t)bh * S_ + s0 + rg * 32 + col) * DK_ + koff;
#pragma unroll
            for (int i = 0; i < 4; ++i)
                qf[rg][i] = *reinterpret_cast<const bf16x8*>(qp + 16 * i);
        }

        for (int st = 0; st <= qq; ++st) {
            const int t0 = st * 256;
            const int ct0 = t0 + w * 64;
            const bool active = (st < qq) || (w <= rb);
            if (active) {
                f32x16 acc[2][2] = {{{}, {}}, {{}, {}}};
#pragma unroll
                for (int cg = 0; cg < 2; ++cg) {
                    const unsigned short* kp = kb + ((size_t)bh * S_ + ct0 + cg * 32 + col) * DK_ + koff;
                    bf16x8 kf0 = *reinterpret_cast<const bf16x8*>(kp);
                    bf16x8 kf1 = *reinterpret_cast<const bf16x8*>(kp + 16);
                    bf16x8 kf2 = *reinterpret_cast<const bf16x8*>(kp + 32);
                    bf16x8 kf3 = *reinterpret_cast<const bf16x8*>(kp + 48);
#pragma unroll
                    for (int rg = 0; rg < 2; ++rg) {
                        acc[rg][cg] = __builtin_amdgcn_mfma_f32_32x32x16_bf16(qf[rg][0], kf0, acc[rg][cg], 0, 0, 0);
                        acc[rg][cg] = __builtin_amdgcn_mfma_f32_32x32x16_bf16(qf[rg][1], kf1, acc[rg][cg], 0, 0, 0);
                        acc[rg][cg] = __builtin_amdgcn_mfma_f32_32x32x16_bf16(qf[rg][2], kf2, acc[rg][cg], 0, 0, 0);
                        acc[rg][cg] = __builtin_amdgcn_mfma_f32_32x32x16_bf16(qf[rg][3], kf3, acc[rg][cg], 0, 0, 0);
                    }
                }
                if (st < qq || w < rb) {
#pragma unroll
                    for (int rg = 0; rg < 2; ++rg) {
#pragma unroll
                        for (int cg = 0; cg < 2; ++cg) {
                            const float sc = th[s0 + rg * 32 - ct0 - cg * 32];
#pragma unroll
                            for (int r = 0; r < 16; ++r)
                                tile[(rg * 32 + rowDv[r]) * 256 + w * 64 + cg * 32 + col] =
                                    acc[rg][cg][r] * grc[r] * sc;
                        }
                    }
                } else {
                    // diagonal wave: masked gather path
#pragma unroll
                    for (int rg = 0; rg < 2; ++rg) {
#pragma unroll
                        for (int cg = 0; cg < 2; ++cg) {
                            const int dbase = 32 * (rg - cg);
#pragma unroll
                            for (int r = 0; r < 16; ++r) {
                                int d = dbase + rowDv[r] - col;
                                float v = (d >= 0) ? acc[rg][cg][r] * th[d] : 0.0f;
                                tile[(rg * 32 + rowDv[r]) * 256 + w * 64 + cg * 32 + col] = v;
                            }
                        }
                    }
                }
            } else {
                // w > rb in the diagonal supertile: quadrant is all zero
                f32x4 z = {0.f, 0.f, 0.f, 0.f};
#pragma unroll
                for (int i = 0; i < 16; ++i) {
                    int r = i * 4 + (lane >> 4);
                    int cc = (lane & 15) * 4;
                    *reinterpret_cast<f32x4*>(&tile[r * 256 + w * 64 + cc]) = z;
                }
            }
            __syncthreads();
#pragma unroll
            for (int r = 0; r < 16; ++r) {
                int row = w * 16 + r;
                f32x4 v = *reinterpret_cast<const f32x4*>(&tile[row * 256 + lane * 4]);
                *reinterpret_cast<f32x4*>(ablk + (size_t)(s0 + row) * S_ + t0 + lane * 4) = v;
            }
            __syncthreads();
        }
    }
}

extern "C" void kernel_launch(void* const* d_in, const int* in_sizes, int n_in,
                              void* d_out, int out_size, void* d_ws, size_t ws_size,
                              hipStream_t stream) {
    const float* x  = (const float*)d_in[0];
    const float* wq = (const float*)d_in[1];
    const float* wk = (const float*)d_in[2];

    char* ws = (char*)d_ws;
    unsigned short* xb  = (unsigned short*)(ws);               //  8,388,608 B
    unsigned short* wqT = (unsigned short*)(ws + 8388608);     //    524,288 B
    unsigned short* wkT = (unsigned short*)(ws + 8912896);     //    524,288 B
    unsigned short* qb  = (unsigned short*)(ws + 9437184);     //  8,388,608 B
    unsigned short* kb  = (unsigned short*)(ws + 17825792);    //  8,388,608 B
    float*          tab = (float*)(ws + 26214400);             //     65,536 B

    float* out0 = (float*)d_out;
    float* aout = (float*)d_out + (size_t)B_ * S_ * D_;

    hipLaunchKernelGGL(k_zero, dim3((B_*S_*D_/4 + 255)/256), dim3(256), 0, stream,
                       (float4*)out0, B_*S_*D_/4);
    hipLaunchKernelGGL(k_fill_upper, dim3(112, 32), dim3(256), 0, stream, aout);
    hipLaunchKernelGGL(k_convert_x, dim3((B_*S_*D_/4 + 255)/256), dim3(256), 0, stream,
                       x, xb, B_*S_*D_/4);
    hipLaunchKernelGGL(k_transpose_w, dim3((2*H_*DK_*D_ + 255)/256), dim3(256), 0, stream,
                       wq, wk, wqT, wkT);
    hipLaunchKernelGGL(k_decay, dim3((H_*S_ + 255)/256), dim3(256), 0, stream, tab);
    hipLaunchKernelGGL(k_proj, dim3(B_*S_/32, 2), dim3(256), 0, stream,
                       xb, wqT, wkT, qb, kb);
    hipLaunchKernelGGL(k_score, dim3(512), dim3(256), 0, stream,
                       qb, kb, tab, aout);
}